// Round 1
// baseline (245.836 us; speedup 1.0000x reference)
//
#include <hip/hip_runtime.h>

typedef unsigned short u16;
typedef unsigned int u32;
typedef float f32x4 __attribute__((ext_vector_type(4)));
typedef __bf16 bf16x8 __attribute__((ext_vector_type(8)));

#define NU 4096
#define DD 256
#define BB 8192

__device__ inline u16 f2b(float f) {
    u32 u = __builtin_bit_cast(u32, f);
    u32 r = (u + 0x7fffu + ((u >> 16) & 1u)) >> 16;
    return (u16)r;
}
__device__ inline float lrelu(float x) { return x > 0.f ? x : 0.2f * x; }

// f32 -> bf16 flat convert (8 elems/thread)
__global__ __launch_bounds__(256) void k_conv(const float* __restrict__ in, u16* __restrict__ out, int n8) {
    int i = blockIdx.x * 256 + threadIdx.x;
    if (i < n8) {
        const float4 v0 = *(const float4*)(in + (size_t)i * 8);
        const float4 v1 = *(const float4*)(in + (size_t)i * 8 + 4);
        u16 u[8] = {f2b(v0.x), f2b(v0.y), f2b(v0.z), f2b(v0.w),
                    f2b(v1.x), f2b(v1.y), f2b(v1.z), f2b(v1.w)};
        *(uint4*)(out + (size_t)i * 8) = *(uint4*)u;
    }
}

// f32 [R][C] -> bf16 [C][R] transpose-convert
__global__ __launch_bounds__(256) void k_tconv(const float* __restrict__ in, u16* __restrict__ out, int R, int C) {
    __shared__ float t[64][65];
    int rb = blockIdx.x * 64, cb = blockIdx.y * 64;
    int tid = threadIdx.x;
    for (int k = 0; k < 16; ++k) {
        int idx = k * 256 + tid;
        int lr = idx >> 6, lc = idx & 63;
        t[lr][lc] = in[(size_t)(rb + lr) * C + cb + lc];
    }
    __syncthreads();
    for (int k = 0; k < 16; ++k) {
        int idx = k * 256 + tid;
        int lr = idx >> 6, lc = idx & 63;
        out[(size_t)(cb + lr) * R + rb + lc] = f2b(t[lc][lr]);
    }
}

// u[b][in] = sum_out W[in][out] * a_half[out]   (b: 0=s1,1=s2,2=c1,3=c2)
__global__ __launch_bounds__(256) void k_uvec(const float* __restrict__ soc_W, const float* __restrict__ soc_a,
                                              const float* __restrict__ cnt_W, const float* __restrict__ cnt_a,
                                              float* __restrict__ uvec) {
    int b = blockIdx.x;
    const float* W = (b < 2) ? soc_W : cnt_W;
    const float* a = ((b < 2) ? soc_a : cnt_a) + (b & 1) * 256;
    __shared__ float sa[256];
    int tid = threadIdx.x, lane = tid & 63, wv = tid >> 6;
    sa[tid] = a[tid];
    __syncthreads();
    for (int rr = 0; rr < 64; ++rr) {
        int in = wv * 64 + rr;
        float4 w4 = *(const float4*)(W + (size_t)in * 256 + lane * 4);
        float acc = w4.x * sa[lane * 4] + w4.y * sa[lane * 4 + 1] + w4.z * sa[lane * 4 + 2] + w4.w * sa[lane * 4 + 3];
#pragma unroll
        for (int off = 32; off; off >>= 1) acc += __shfl_down(acc, off);
        if (lane == 0) uvec[b * 256 + in] = acc;
    }
}

// bf16 MFMA GEMM: C[M][N] = A[M][K] @ Bt[N][K]^T + bias; optional f32/bf16/bf16-transposed outputs
__global__ __launch_bounds__(256) void k_gemm(const u16* __restrict__ A, const u16* __restrict__ Bt,
                                              const float* __restrict__ bias,
                                              float* __restrict__ Cf, u16* __restrict__ Cb, u16* __restrict__ Cbt,
                                              int M, int N, int K, int relu) {
    __shared__ u16 As[64 * 64];
    __shared__ u16 Bs[64 * 64];
    const int tid = threadIdx.x;
    const int lane = tid & 63, wv = tid >> 6;
    const int bm = blockIdx.x * 64, bn = blockIdx.y * 64;
    const int wm = (wv >> 1) * 32, wn = (wv & 1) * 32;
    f32x4 acc[2][2];
#pragma unroll
    for (int i = 0; i < 2; i++)
#pragma unroll
        for (int j = 0; j < 2; j++) acc[i][j] = f32x4{0.f, 0.f, 0.f, 0.f};

    char* Ab = (char*)As;
    char* Bb = (char*)Bs;
    const int r = tid >> 2;
    const int ib0 = (tid & 3) * 32;          // byte offset within 128B row
    const int swz = (r & 7) << 4;

    for (int k0 = 0; k0 < K; k0 += 64) {
        const uint4* ga = (const uint4*)(A + (size_t)(bm + r) * K + k0 + (ib0 >> 1));
        const uint4* gb = (const uint4*)(Bt + (size_t)(bn + r) * K + k0 + (ib0 >> 1));
        uint4 va0 = ga[0], va1 = ga[1];
        uint4 vb0 = gb[0], vb1 = gb[1];
        __syncthreads();
        *(uint4*)(Ab + r * 128 + ((ib0) ^ swz)) = va0;
        *(uint4*)(Ab + r * 128 + ((ib0 + 16) ^ swz)) = va1;
        *(uint4*)(Bb + r * 128 + ((ib0) ^ swz)) = vb0;
        *(uint4*)(Bb + r * 128 + ((ib0 + 16) ^ swz)) = vb1;
        __syncthreads();
#pragma unroll
        for (int kh = 0; kh < 2; ++kh) {
            bf16x8 af[2], bfr[2];
#pragma unroll
            for (int mf = 0; mf < 2; ++mf) {
                int row = wm + mf * 16 + (lane & 15);
                int kb = kh * 64 + ((lane >> 4) << 4);
                af[mf] = *(const bf16x8*)(Ab + row * 128 + (kb ^ ((row & 7) << 4)));
            }
#pragma unroll
            for (int nf = 0; nf < 2; ++nf) {
                int row = wn + nf * 16 + (lane & 15);
                int kb = kh * 64 + ((lane >> 4) << 4);
                bfr[nf] = *(const bf16x8*)(Bb + row * 128 + (kb ^ ((row & 7) << 4)));
            }
#pragma unroll
            for (int mf = 0; mf < 2; ++mf)
#pragma unroll
                for (int nf = 0; nf < 2; ++nf)
                    acc[mf][nf] = __builtin_amdgcn_mfma_f32_16x16x32_bf16(af[mf], bfr[nf], acc[mf][nf], 0, 0, 0);
        }
    }
#pragma unroll
    for (int mf = 0; mf < 2; ++mf) {
#pragma unroll
        for (int nf = 0; nf < 2; ++nf) {
            int col = bn + wn + nf * 16 + (lane & 15);
            int row0 = bm + wm + mf * 16 + ((lane >> 4) << 2);
            float bv = bias ? bias[col] : 0.f;
            float v[4];
#pragma unroll
            for (int q = 0; q < 4; ++q) {
                float x = acc[mf][nf][q] + bv;
                if (relu) x = fmaxf(x, 0.f);
                v[q] = x;
                if (Cf) Cf[(size_t)(row0 + q) * N + col] = x;
                if (Cb) Cb[(size_t)(row0 + q) * N + col] = f2b(x);
            }
            if (Cbt) {
                uint2 p;
                p.x = (u32)f2b(v[0]) | ((u32)f2b(v[1]) << 16);
                p.y = (u32)f2b(v[2]) | ((u32)f2b(v[3]) << 16);
                *(uint2*)(Cbt + (size_t)col * M + row0) = p;
            }
        }
    }
}

// a-vector GEMVs: w0: a1_s=h_u.u_s1  w1: a2_s=h_u.u_s2  w2: a1_c=h_u.u_c1  w3: a2_c=h_i.u_c2
__global__ __launch_bounds__(256) void k_gemv_a(const float* __restrict__ h_u, const float* __restrict__ h_i,
                                                const float* __restrict__ uvec, float* __restrict__ avec) {
    int tid = threadIdx.x, lane = tid & 63, wv = tid >> 6;
    int ib = blockIdx.x * 64;
    const float* H = (wv == 3) ? h_i : h_u;
    const float* u = uvec + wv * 256;
    float4 u4 = *(const float4*)(u + lane * 4);
    for (int rr = 0; rr < 64; ++rr) {
        int row = ib + rr;
        float4 h4 = *(const float4*)(H + (size_t)row * 256 + lane * 4);
        float acc = h4.x * u4.x + h4.y * u4.y + h4.z * u4.z + h4.w * u4.w;
#pragma unroll
        for (int off = 32; off; off >>= 1) acc += __shfl_down(acc, off);
        if (lane == 0) avec[wv * 4096 + row] = acc;
    }
}

__global__ __launch_bounds__(256) void k_maxfinal(const float* __restrict__ avec, float* __restrict__ Mh) {
    __shared__ float red[256];
    int t = threadIdx.x;
    for (int z = 0; z < 2; ++z) {
        const float* a2 = avec + z * 8192 + 4096;
        float m = -1e30f;
        for (int i = t; i < 4096; i += 256) m = fmaxf(m, a2[i]);
        red[t] = m;
        __syncthreads();
        for (int s = 128; s; s >>= 1) {
            if (t < s) red[t] = fmaxf(red[t], red[t + s]);
            __syncthreads();
        }
        if (t == 0) Mh[z] = red[0];
        __syncthreads();
    }
}

// denom scan: fixed shift m̂_i = lrelu(a1_i + max_all a2)  (>= masked max -> exp<=1, softmax-identical)
__global__ __launch_bounds__(256) void k_scan(const int* __restrict__ adjS, const int* __restrict__ adjC,
                                              const float* __restrict__ avec, const float* __restrict__ Mh,
                                              float* __restrict__ dpart) {
    int z = blockIdx.z;
    const int* adj = z ? adjC : adjS;
    const float* a1 = avec + z * 8192;
    const float* a2 = a1 + 4096;
    float mhg = Mh[z];
    int ib = blockIdx.x * 64, jb = blockIdx.y * 1024;
    int lane = threadIdx.x & 63, wv = threadIdx.x >> 6;
    for (int rr = 0; rr < 16; ++rr) {
        int row = ib + wv * 16 + rr;
        float a1r = a1[row];
        float mr = lrelu(a1r + mhg);
        float acc = 0.f;
        for (int jj = 0; jj < 16; ++jj) {
            int j = jb + jj * 64 + lane;
            int ad = adj[(size_t)row * 4096 + j];
            float e = lrelu(a1r + a2[j]) - mr;
            acc += ad ? __expf(e) : 0.f;
        }
#pragma unroll
        for (int off = 32; off; off >>= 1) acc += __shfl_down(acc, off);
        if (lane == 0) dpart[((size_t)z * 4 + blockIdx.y) * 4096 + row] = acc;
    }
}

__global__ __launch_bounds__(256) void k_dreduce(const float* __restrict__ dpart, float* __restrict__ invd) {
    int i = blockIdx.x * 256 + threadIdx.x;  // 0..8191
    if (i < 8192) {
        int z = i >> 12, r = i & 4095;
        float d = 0.f;
#pragma unroll
        for (int s = 0; s < 4; ++s) d += dpart[((size_t)z * 4 + s) * 4096 + r];
        invd[i] = d > 0.f ? 1.f / d : 0.f;
    }
}

// fused: alpha write (normalized f32) + msg = alpha @ P  via bf16 MFMA
__global__ __launch_bounds__(256) void k_flash(const int* __restrict__ adjS, const int* __restrict__ adjC,
                                               const float* __restrict__ avec, const float* __restrict__ Mh,
                                               const float* __restrict__ invd,
                                               const u16* __restrict__ WhT, const u16* __restrict__ WiT,
                                               float* __restrict__ out, float* __restrict__ msgpart) {
    const int z = blockIdx.z;
    const int ib = blockIdx.x * 64;
    const int jb = blockIdx.y * 1024;
    const int tid = threadIdx.x, lane = tid & 63, wv = tid >> 6;
    const int* adj = z ? adjC : adjS;
    const float* a1 = avec + z * 8192;
    const float* a2 = a1 + 4096;
    const u16* Pt = z ? WiT : WhT;
    float* alpha = out + 8192 + (size_t)z * 16777216;
    const float mhg = Mh[z];
    const float* inv = invd + z * 4096;

    __shared__ u16 Aex[64 * 64];
    __shared__ float s_a1[64], s_mh[64], s_inv[64];
    if (tid < 64) {
        float a = a1[ib + tid];
        s_a1[tid] = a;
        s_mh[tid] = lrelu(a + mhg);
        s_inv[tid] = inv[ib + tid];
    }
    __syncthreads();

    f32x4 acc[4][4];
#pragma unroll
    for (int i = 0; i < 4; i++)
#pragma unroll
        for (int j = 0; j < 4; j++) acc[i][j] = f32x4{0.f, 0.f, 0.f, 0.f};

    char* Ab = (char*)Aex;
    const int rbase = (tid >> 5) * 8;
    const int jp = (tid & 31) * 2;

    for (int js = 0; js < 16; ++js) {
        const int j0 = jb + js * 64;
        float2 a2v = *(const float2*)(a2 + j0 + jp);
#pragma unroll
        for (int rr = 0; rr < 8; ++rr) {
            int rloc = rbase + rr;
            int2 ad = *(const int2*)(adj + (size_t)(ib + rloc) * 4096 + j0 + jp);
            float a1r = s_a1[rloc], mr = s_mh[rloc], ivr = s_inv[rloc];
            float e0 = lrelu(a1r + a2v.x) - mr;
            float e1 = lrelu(a1r + a2v.y) - mr;
            float x0 = ad.x ? __expf(e0) : 0.f;
            float x1 = ad.y ? __expf(e1) : 0.f;
            float al0 = x0 * ivr, al1 = x1 * ivr;
            *(float2*)(alpha + (size_t)(ib + rloc) * 4096 + j0 + jp) = float2{al0, al1};
            u32 pk = (u32)f2b(al0) | ((u32)f2b(al1) << 16);
            *(u32*)(Ab + rloc * 128 + ((jp * 2) ^ ((rloc & 7) << 4))) = pk;
        }
        __syncthreads();
#pragma unroll
        for (int kh = 0; kh < 2; ++kh) {
            bf16x8 bfr[4];
#pragma unroll
            for (int nf = 0; nf < 4; ++nf) {
                int n = wv * 64 + nf * 16 + (lane & 15);
                bfr[nf] = *(const bf16x8*)(Pt + (size_t)n * 4096 + j0 + kh * 32 + ((lane >> 4) << 3));
            }
#pragma unroll
            for (int mf = 0; mf < 4; ++mf) {
                int row = mf * 16 + (lane & 15);
                int kb = kh * 64 + ((lane >> 4) << 4);
                bf16x8 af = *(const bf16x8*)(Ab + row * 128 + (kb ^ ((row & 7) << 4)));
#pragma unroll
                for (int nf = 0; nf < 4; ++nf)
                    acc[mf][nf] = __builtin_amdgcn_mfma_f32_16x16x32_bf16(af, bfr[nf], acc[mf][nf], 0, 0, 0);
            }
        }
        __syncthreads();
    }
    float* mp = msgpart + ((size_t)(z * 4 + blockIdx.y) * 4096 + ib) * 256;
#pragma unroll
    for (int mf = 0; mf < 4; ++mf) {
        int row = mf * 16 + ((lane >> 4) << 2);
#pragma unroll
        for (int nf = 0; nf < 4; ++nf) {
            int col = wv * 64 + nf * 16 + (lane & 15);
#pragma unroll
            for (int q = 0; q < 4; ++q) mp[(size_t)(row + q) * 256 + col] = acc[mf][nf][q];
        }
    }
}

// h_u_out = elu(soc+cnt+h_u) + aq*sigmoid(q@gW+gb)*(q@qW+qb)  -> bf16
__global__ __launch_bounds__(256) void k_post(const float* __restrict__ msgpart, const float* __restrict__ h_u,
                                              const float* __restrict__ q_u,
                                              const float* __restrict__ gate_W, const float* __restrict__ gate_b,
                                              const float* __restrict__ qproj_W, const float* __restrict__ qproj_b,
                                              const float* __restrict__ alpha_q, u16* __restrict__ huo_b) {
    int i = blockIdx.x;
    int n = threadIdx.x;
    float s = 0.f;
#pragma unroll
    for (int p = 0; p < 8; ++p) s += msgpart[((size_t)p * 4096 + i) * 256 + n];
    float v = s + h_u[(size_t)i * 256 + n];
    v = v > 0.f ? v : expm1f(v);
    float q0 = q_u[i * 4 + 0], q1 = q_u[i * 4 + 1], q2 = q_u[i * 4 + 2], q3 = q_u[i * 4 + 3];
    float g = q0 * gate_W[n] + q1 * gate_W[256 + n] + q2 * gate_W[512 + n] + q3 * gate_W[768 + n] + gate_b[n];
    g = 1.f / (1.f + __expf(-g));
    float qp = q0 * qproj_W[n] + q1 * qproj_W[256 + n] + q2 * qproj_W[512 + n] + q3 * qproj_W[768 + n] + qproj_b[n];
    float o = v + alpha_q[0] * g * qp;
    huo_b[(size_t)i * 256 + n] = f2b(o);
}

__global__ __launch_bounds__(256) void k_gather(const u16* __restrict__ huo, const u16* __restrict__ h_i_b,
                                                const int* __restrict__ uidx, const int* __restrict__ iidx,
                                                u16* __restrict__ cat) {
    int gid = blockIdx.x * 256 + threadIdx.x;
    int b = gid >> 6, c = gid & 63;
    int k = c * 8;
    const u16* src = (k < 256) ? (huo + (size_t)uidx[b] * 256 + k) : (h_i_b + (size_t)iidx[b] * 256 + (k - 256));
    *(uint4*)(cat + (size_t)b * 512 + k) = *(const uint4*)src;
}

__global__ __launch_bounds__(256) void k_rhat(const float* __restrict__ hid, const float* __restrict__ W2,
                                              const float* __restrict__ b2, float* __restrict__ out) {
    int row = blockIdx.x * 4 + (threadIdx.x >> 6);
    int lane = threadIdx.x & 63;
    float4 h = *(const float4*)(hid + (size_t)row * 256 + lane * 4);
    float4 w = *(const float4*)(W2 + lane * 4);
    float acc = h.x * w.x + h.y * w.y + h.z * w.z + h.w * w.w;
#pragma unroll
    for (int off = 32; off; off >>= 1) acc += __shfl_down(acc, off);
    if (lane == 0) out[row] = 1.f + 4.f / (1.f + __expf(-(acc + b2[0])));
}

extern "C" void kernel_launch(void* const* d_in, const int* in_sizes, int n_in,
                              void* d_out, int out_size, void* d_ws, size_t ws_size,
                              hipStream_t stream) {
    const float* x_u = (const float*)d_in[0];
    const float* x_i = (const float*)d_in[1];
    const int* adjS = (const int*)d_in[2];
    const int* adjC = (const int*)d_in[3];
    const int* uidx = (const int*)d_in[4];
    const int* iidx = (const int*)d_in[5];
    const float* q_u = (const float*)d_in[6];
    const float* user_W = (const float*)d_in[7];
    const float* user_b = (const float*)d_in[8];
    const float* item_W = (const float*)d_in[9];
    const float* item_b = (const float*)d_in[10];
    const float* soc_W = (const float*)d_in[11];
    const float* soc_a = (const float*)d_in[12];
    const float* cnt_W = (const float*)d_in[13];
    const float* cnt_a = (const float*)d_in[14];
    const float* gate_W = (const float*)d_in[15];
    const float* gate_b = (const float*)d_in[16];
    const float* qproj_W = (const float*)d_in[17];
    const float* qproj_b = (const float*)d_in[18];
    const float* alpha_q = (const float*)d_in[19];
    const float* pred_W1 = (const float*)d_in[20];
    const float* pred_b1 = (const float*)d_in[21];
    const float* pred_W2 = (const float*)d_in[22];
    const float* pred_b2 = (const float*)d_in[23];
    float* out = (float*)d_out;

    char* w = (char*)d_ws;
    size_t off = 0;
    auto alloc = [&](size_t bytes) -> void* {
        void* p = w + off;
        off = (off + bytes + 255) & ~(size_t)255;
        return p;
    };
    u16* x_u_b = (u16*)alloc((size_t)NU * DD * 2);
    u16* x_i_b = (u16*)alloc((size_t)NU * DD * 2);
    u16* uWt = (u16*)alloc(256 * 256 * 2);
    u16* iWt = (u16*)alloc(256 * 256 * 2);
    u16* sWt = (u16*)alloc(256 * 256 * 2);
    u16* cWt = (u16*)alloc(256 * 256 * 2);
    u16* p1Wt = (u16*)alloc(512 * 256 * 2);
    float* uvec = (float*)alloc(4 * 256 * 4);
    float* h_u_f = (float*)alloc((size_t)NU * DD * 4);
    float* h_i_f = (float*)alloc((size_t)NU * DD * 4);
    u16* h_u_b = (u16*)alloc((size_t)NU * DD * 2);
    u16* h_i_b = (u16*)alloc((size_t)NU * DD * 2);
    u16* WhT = (u16*)alloc((size_t)NU * DD * 2);
    u16* WiT = (u16*)alloc((size_t)NU * DD * 2);
    float* avec = (float*)alloc(4 * 4096 * 4);
    float* Mh = (float*)alloc(2 * 4);
    float* dpart = (float*)alloc((size_t)2 * 4 * 4096 * 4);
    float* invd = (float*)alloc((size_t)2 * 4096 * 4);
    float* msgpart = (float*)alloc((size_t)2 * 4 * 4096 * 256 * 4);
    u16* huo_b = (u16*)alloc((size_t)NU * DD * 2);
    u16* cat_b = (u16*)alloc((size_t)BB * 512 * 2);
    float* hid_f = (float*)alloc((size_t)BB * 256 * 4);
    (void)in_sizes; (void)n_in; (void)out_size; (void)ws_size;

    k_conv<<<512, 256, 0, stream>>>(x_u, x_u_b, NU * DD / 8);
    k_conv<<<512, 256, 0, stream>>>(x_i, x_i_b, NU * DD / 8);
    k_tconv<<<dim3(4, 4), 256, 0, stream>>>(user_W, uWt, 256, 256);
    k_tconv<<<dim3(4, 4), 256, 0, stream>>>(item_W, iWt, 256, 256);
    k_tconv<<<dim3(4, 4), 256, 0, stream>>>(soc_W, sWt, 256, 256);
    k_tconv<<<dim3(4, 4), 256, 0, stream>>>(cnt_W, cWt, 256, 256);
    k_tconv<<<dim3(8, 4), 256, 0, stream>>>(pred_W1, p1Wt, 512, 256);
    k_uvec<<<4, 256, 0, stream>>>(soc_W, soc_a, cnt_W, cnt_a, uvec);

    k_gemm<<<dim3(64, 4), 256, 0, stream>>>(x_u_b, uWt, user_b, h_u_f, h_u_b, nullptr, NU, 256, 256, 0);
    k_gemm<<<dim3(64, 4), 256, 0, stream>>>(x_i_b, iWt, item_b, h_i_f, h_i_b, nullptr, NU, 256, 256, 0);
    k_gemm<<<dim3(64, 4), 256, 0, stream>>>(h_u_b, sWt, nullptr, nullptr, nullptr, WhT, NU, 256, 256, 0);
    k_gemm<<<dim3(64, 4), 256, 0, stream>>>(h_i_b, cWt, nullptr, nullptr, nullptr, WiT, NU, 256, 256, 0);

    k_gemv_a<<<64, 256, 0, stream>>>(h_u_f, h_i_f, uvec, avec);
    k_maxfinal<<<1, 256, 0, stream>>>(avec, Mh);
    k_scan<<<dim3(64, 4, 2), 256, 0, stream>>>(adjS, adjC, avec, Mh, dpart);
    k_dreduce<<<32, 256, 0, stream>>>(dpart, invd);
    k_flash<<<dim3(64, 4, 2), 256, 0, stream>>>(adjS, adjC, avec, Mh, invd, WhT, WiT, out, msgpart);

    k_post<<<4096, 256, 0, stream>>>(msgpart, h_u_f, q_u, gate_W, gate_b, qproj_W, qproj_b, alpha_q, huo_b);
    k_gather<<<2048, 256, 0, stream>>>(huo_b, h_i_b, uidx, iidx, cat_b);
    k_gemm<<<dim3(128, 4), 256, 0, stream>>>(cat_b, p1Wt, pred_b1, hid_f, nullptr, nullptr, BB, 256, 512, 1);
    k_rhat<<<2048, 256, 0, stream>>>(hid_f, pred_W2, pred_b2, out);
}

// Round 2
// 210.794 us; speedup vs baseline: 1.1662x; 1.1662x over previous
//
#include <hip/hip_runtime.h>

typedef unsigned short u16;
typedef unsigned int u32;
typedef unsigned char u8;
typedef float f32x4 __attribute__((ext_vector_type(4)));
typedef __bf16 bf16x8 __attribute__((ext_vector_type(8)));

#define NU 4096
#define DD 256
#define BB 8192

__device__ inline u16 f2b(float f) {
    u32 u = __builtin_bit_cast(u32, f);
    u32 r = (u + 0x7fffu + ((u >> 16) & 1u)) >> 16;
    return (u16)r;
}
__device__ inline float lrelu(float x) { return x > 0.f ? x : 0.2f * x; }

#define BARRIER_LGKM() asm volatile("s_waitcnt lgkmcnt(0)\ns_barrier" ::: "memory")

// f32 -> bf16 flat convert, both x_u and x_i via z
__global__ __launch_bounds__(256) void k_conv(const float* __restrict__ in0, u16* __restrict__ out0,
                                              const float* __restrict__ in1, u16* __restrict__ out1, int n8) {
    const float* in = blockIdx.z ? in1 : in0;
    u16* out = blockIdx.z ? out1 : out0;
    int i = blockIdx.x * 256 + threadIdx.x;
    if (i < n8) {
        const float4 v0 = *(const float4*)(in + (size_t)i * 8);
        const float4 v1 = *(const float4*)(in + (size_t)i * 8 + 4);
        u16 u[8] = {f2b(v0.x), f2b(v0.y), f2b(v0.z), f2b(v0.w),
                    f2b(v1.x), f2b(v1.y), f2b(v1.z), f2b(v1.w)};
        *(uint4*)(out + (size_t)i * 8) = *(uint4*)u;
    }
}

// f32 [R][C] -> bf16 [C][R] transpose-convert, 5 weights via z
__global__ __launch_bounds__(256) void k_tconv(const float* __restrict__ w0, const float* __restrict__ w1,
                                               const float* __restrict__ w2, const float* __restrict__ w3,
                                               const float* __restrict__ w4,
                                               u16* __restrict__ o0, u16* __restrict__ o1, u16* __restrict__ o2,
                                               u16* __restrict__ o3, u16* __restrict__ o4) {
    int z = blockIdx.z;
    const float* in = z == 0 ? w0 : z == 1 ? w1 : z == 2 ? w2 : z == 3 ? w3 : w4;
    u16* out = z == 0 ? o0 : z == 1 ? o1 : z == 2 ? o2 : z == 3 ? o3 : o4;
    int R = (z == 4) ? 512 : 256, C = 256;
    int rb = blockIdx.x * 64, cb = blockIdx.y * 64;
    if (rb >= R) return;
    __shared__ float t[64][65];
    int tid = threadIdx.x;
    for (int k = 0; k < 16; ++k) {
        int idx = k * 256 + tid;
        int lr = idx >> 6, lc = idx & 63;
        t[lr][lc] = in[(size_t)(rb + lr) * C + cb + lc];
    }
    __syncthreads();
    for (int k = 0; k < 16; ++k) {
        int idx = k * 256 + tid;
        int lr = idx >> 6, lc = idx & 63;
        out[(size_t)(cb + lr) * R + rb + lc] = f2b(t[lc][lr]);
    }
}

// u[b][in] = sum_out W[in][out] * a_half[out]
__global__ __launch_bounds__(256) void k_uvec(const float* __restrict__ soc_W, const float* __restrict__ soc_a,
                                              const float* __restrict__ cnt_W, const float* __restrict__ cnt_a,
                                              float* __restrict__ uvec) {
    int b = blockIdx.x;
    const float* W = (b < 2) ? soc_W : cnt_W;
    const float* a = ((b < 2) ? soc_a : cnt_a) + (b & 1) * 256;
    __shared__ float sa[256];
    int tid = threadIdx.x, lane = tid & 63, wv = tid >> 6;
    sa[tid] = a[tid];
    __syncthreads();
    for (int rr = 0; rr < 64; ++rr) {
        int in = wv * 64 + rr;
        float4 w4 = *(const float4*)(W + (size_t)in * 256 + lane * 4);
        float acc = w4.x * sa[lane * 4] + w4.y * sa[lane * 4 + 1] + w4.z * sa[lane * 4 + 2] + w4.w * sa[lane * 4 + 3];
#pragma unroll
        for (int off = 32; off; off >>= 1) acc += __shfl_down(acc, off);
        if (lane == 0) uvec[b * 256 + in] = acc;
    }
}

// batched (z=2) bf16 MFMA GEMM: C[M][N] = A[M][K] @ Bt[N][K]^T + bias
__global__ __launch_bounds__(256) void k_gemm(const u16* __restrict__ A0, const u16* __restrict__ B0,
                                              const float* __restrict__ bias0, float* __restrict__ Cf0,
                                              u16* __restrict__ Cb0, u16* __restrict__ Cbt0,
                                              const u16* __restrict__ A1, const u16* __restrict__ B1,
                                              const float* __restrict__ bias1, float* __restrict__ Cf1,
                                              u16* __restrict__ Cb1, u16* __restrict__ Cbt1,
                                              int M, int N, int K) {
    const int z = blockIdx.z;
    const u16* A = z ? A1 : A0;
    const u16* Bt = z ? B1 : B0;
    const float* bias = z ? bias1 : bias0;
    float* Cf = z ? Cf1 : Cf0;
    u16* Cb = z ? Cb1 : Cb0;
    u16* Cbt = z ? Cbt1 : Cbt0;

    __shared__ u16 As[64 * 64];
    __shared__ u16 Bs[64 * 64];
    const int tid = threadIdx.x;
    const int lane = tid & 63, wv = tid >> 6;
    const int bm = blockIdx.x * 64, bn = blockIdx.y * 64;
    const int wm = (wv >> 1) * 32, wn = (wv & 1) * 32;
    f32x4 acc[2][2];
#pragma unroll
    for (int i = 0; i < 2; i++)
#pragma unroll
        for (int j = 0; j < 2; j++) acc[i][j] = f32x4{0.f, 0.f, 0.f, 0.f};

    char* Ab = (char*)As;
    char* Bb = (char*)Bs;
    const int r = tid >> 2;
    const int ib0 = (tid & 3) * 32;
    const int swz = (r & 7) << 4;

    for (int k0 = 0; k0 < K; k0 += 64) {
        const uint4* ga = (const uint4*)(A + (size_t)(bm + r) * K + k0 + (ib0 >> 1));
        const uint4* gb = (const uint4*)(Bt + (size_t)(bn + r) * K + k0 + (ib0 >> 1));
        uint4 va0 = ga[0], va1 = ga[1];
        uint4 vb0 = gb[0], vb1 = gb[1];
        __syncthreads();
        *(uint4*)(Ab + r * 128 + ((ib0) ^ swz)) = va0;
        *(uint4*)(Ab + r * 128 + ((ib0 + 16) ^ swz)) = va1;
        *(uint4*)(Bb + r * 128 + ((ib0) ^ swz)) = vb0;
        *(uint4*)(Bb + r * 128 + ((ib0 + 16) ^ swz)) = vb1;
        __syncthreads();
#pragma unroll
        for (int kh = 0; kh < 2; ++kh) {
            bf16x8 af[2], bfr[2];
#pragma unroll
            for (int mf = 0; mf < 2; ++mf) {
                int row = wm + mf * 16 + (lane & 15);
                int kb = kh * 64 + ((lane >> 4) << 4);
                af[mf] = *(const bf16x8*)(Ab + row * 128 + (kb ^ ((row & 7) << 4)));
            }
#pragma unroll
            for (int nf = 0; nf < 2; ++nf) {
                int row = wn + nf * 16 + (lane & 15);
                int kb = kh * 64 + ((lane >> 4) << 4);
                bfr[nf] = *(const bf16x8*)(Bb + row * 128 + (kb ^ ((row & 7) << 4)));
            }
#pragma unroll
            for (int mf = 0; mf < 2; ++mf)
#pragma unroll
                for (int nf = 0; nf < 2; ++nf)
                    acc[mf][nf] = __builtin_amdgcn_mfma_f32_16x16x32_bf16(af[mf], bfr[nf], acc[mf][nf], 0, 0, 0);
        }
    }
#pragma unroll
    for (int mf = 0; mf < 2; ++mf) {
#pragma unroll
        for (int nf = 0; nf < 2; ++nf) {
            int col = bn + wn + nf * 16 + (lane & 15);
            int row0 = bm + wm + mf * 16 + ((lane >> 4) << 2);
            float bv = bias ? bias[col] : 0.f;
            float v[4];
#pragma unroll
            for (int q = 0; q < 4; ++q) {
                float x = acc[mf][nf][q] + bv;
                v[q] = x;
                if (Cf) Cf[(size_t)(row0 + q) * N + col] = x;
                if (Cb) Cb[(size_t)(row0 + q) * N + col] = f2b(x);
            }
            if (Cbt) {
                uint2 p;
                p.x = (u32)f2b(v[0]) | ((u32)f2b(v[1]) << 16);
                p.y = (u32)f2b(v[2]) | ((u32)f2b(v[3]) << 16);
                *(uint2*)(Cbt + (size_t)col * M + row0) = p;
            }
        }
    }
}

// a-vector GEMVs
__global__ __launch_bounds__(256) void k_gemv_a(const float* __restrict__ h_u, const float* __restrict__ h_i,
                                                const float* __restrict__ uvec, float* __restrict__ avec) {
    int tid = threadIdx.x, lane = tid & 63, wv = tid >> 6;
    int ib = blockIdx.x * 64;
    const float* H = (wv == 3) ? h_i : h_u;
    const float* u = uvec + wv * 256;
    float4 u4 = *(const float4*)(u + lane * 4);
    for (int rr = 0; rr < 64; ++rr) {
        int row = ib + rr;
        float4 h4 = *(const float4*)(H + (size_t)row * 256 + lane * 4);
        float acc = h4.x * u4.x + h4.y * u4.y + h4.z * u4.z + h4.w * u4.w;
#pragma unroll
        for (int off = 32; off; off >>= 1) acc += __shfl_down(acc, off);
        if (lane == 0) avec[wv * 4096 + row] = acc;
    }
}

__global__ __launch_bounds__(256) void k_maxfinal(const float* __restrict__ avec, float* __restrict__ Mh) {
    __shared__ float red[256];
    int t = threadIdx.x;
    for (int z = 0; z < 2; ++z) {
        const float* a2 = avec + z * 8192 + 4096;
        float m = -1e30f;
        for (int i = t; i < 4096; i += 256) m = fmaxf(m, a2[i]);
        red[t] = m;
        __syncthreads();
        for (int s = 128; s; s >>= 1) {
            if (t < s) red[t] = fmaxf(red[t], red[t + s]);
            __syncthreads();
        }
        if (t == 0) Mh[z] = red[0];
        __syncthreads();
    }
}

// denom scan + bit-pack adjacency (1 bit/edge)
__global__ __launch_bounds__(256) void k_scan(const int* __restrict__ adjS, const int* __restrict__ adjC,
                                              const float* __restrict__ avec, const float* __restrict__ Mh,
                                              float* __restrict__ dpart, u8* __restrict__ bits) {
    int z = blockIdx.z;
    const int* adj = z ? adjC : adjS;
    const float* a1 = avec + z * 8192;
    const float* a2 = a1 + 4096;
    u8* bz = bits + (size_t)z * 2097152;
    float mhg = Mh[z];
    int ib = blockIdx.x * 64, jb = blockIdx.y * 512;
    int lane = threadIdx.x & 63, wv = threadIdx.x >> 6;
    float4 A0 = *(const float4*)(a2 + jb + lane * 8);
    float4 A1 = *(const float4*)(a2 + jb + lane * 8 + 4);
    for (int rr = 0; rr < 16; ++rr) {
        int row = ib + wv * 16 + rr;
        float a1r = a1[row];
        float mr = lrelu(a1r + mhg);
        const int4* p = (const int4*)(adj + (size_t)row * 4096 + jb + lane * 8);
        int4 v0 = p[0], v1 = p[1];
        u32 b = (u32)(v0.x != 0) | ((u32)(v0.y != 0) << 1) | ((u32)(v0.z != 0) << 2) | ((u32)(v0.w != 0) << 3) |
                ((u32)(v1.x != 0) << 4) | ((u32)(v1.y != 0) << 5) | ((u32)(v1.z != 0) << 6) | ((u32)(v1.w != 0) << 7);
        bz[(size_t)row * 512 + (jb >> 3) + lane] = (u8)b;
        float acc = 0.f;
        acc += v0.x ? __expf(lrelu(a1r + A0.x) - mr) : 0.f;
        acc += v0.y ? __expf(lrelu(a1r + A0.y) - mr) : 0.f;
        acc += v0.z ? __expf(lrelu(a1r + A0.z) - mr) : 0.f;
        acc += v0.w ? __expf(lrelu(a1r + A0.w) - mr) : 0.f;
        acc += v1.x ? __expf(lrelu(a1r + A1.x) - mr) : 0.f;
        acc += v1.y ? __expf(lrelu(a1r + A1.y) - mr) : 0.f;
        acc += v1.z ? __expf(lrelu(a1r + A1.z) - mr) : 0.f;
        acc += v1.w ? __expf(lrelu(a1r + A1.w) - mr) : 0.f;
#pragma unroll
        for (int off = 32; off; off >>= 1) acc += __shfl_down(acc, off);
        if (lane == 0) dpart[((size_t)z * 8 + blockIdx.y) * 4096 + row] = acc;
    }
}

__global__ __launch_bounds__(256) void k_dreduce(const float* __restrict__ dpart, float* __restrict__ invd) {
    int i = blockIdx.x * 256 + threadIdx.x;
    if (i < 8192) {
        int z = i >> 12, r = i & 4095;
        float d = 0.f;
#pragma unroll
        for (int s = 0; s < 8; ++s) d += dpart[((size_t)z * 8 + s) * 4096 + r];
        invd[i] = d > 0.f ? 1.f / d : 0.f;
    }
}

// fused: alpha write (normalized f32) + msg = alpha @ P via bf16 MFMA
// 64 rows x 1024 cols per block, 8 waves, double-buffered LDS, 1 lgkm-barrier/js
__global__ __launch_bounds__(512, 4) void k_flash(const u8* __restrict__ bits,
                                                  const float* __restrict__ avec, const float* __restrict__ Mh,
                                                  const float* __restrict__ invd,
                                                  const u16* __restrict__ WhT, const u16* __restrict__ WiT,
                                                  float* __restrict__ out, float* __restrict__ msgpart) {
    const int z = blockIdx.z;
    const int ib = blockIdx.x * 64;
    const int jb = blockIdx.y * 1024;
    const int tid = threadIdx.x, lane = tid & 63, wv = tid >> 6;
    const u8* bz = bits + (size_t)z * 2097152;
    const float* a1 = avec + z * 8192;
    const float* a2 = a1 + 4096;
    const u16* Pt = z ? WiT : WhT;
    float* alpha = out + 8192 + (size_t)z * 16777216;
    const float mhg = Mh[z];
    const float* inv = invd + z * 4096;

    __shared__ float a2s[1024];
    __shared__ u16 Atile[2 * 64 * 64];
    __shared__ float s_a1[64], s_mr[64], s_inv[64];
    char* Ab = (char*)Atile;

    const int row = wv * 8 + (lane >> 3);   // 0..63 local row
    const int cg = lane & 7;                 // col group (8 cols)
    const int gr = ib + row;
    const int bbase = jb >> 3;

    {
        float2 v = *(const float2*)(a2 + jb + tid * 2);
        *(float2*)(a2s + tid * 2) = v;
        if (tid < 64) {
            float a = a1[ib + tid];
            s_a1[tid] = a;
            s_mr[tid] = lrelu(a + mhg);
            s_inv[tid] = inv[ib + tid];
        }
    }
    __syncthreads();

    f32x4 acc[4][2];
#pragma unroll
    for (int i = 0; i < 4; i++)
#pragma unroll
        for (int j = 0; j < 2; j++) acc[i][j] = f32x4{0.f, 0.f, 0.f, 0.f};

    float4 stA, stB;
    const float a1r = s_a1[row], mr = s_mr[row], ivr = s_inv[row];
    const int wswz = (row & 7) << 4;

    auto compute_tile = [&](int js, int buf) {
        const int j0 = js * 64;
        u32 byte = bz[(size_t)gr * 512 + bbase + js * 8 + cg];
        const float4 a2a = *(const float4*)(a2s + j0 + cg * 8);
        const float4 a2b = *(const float4*)(a2s + j0 + cg * 8 + 4);
        float av[8] = {a2a.x, a2a.y, a2a.z, a2a.w, a2b.x, a2b.y, a2b.z, a2b.w};
        float al[8];
#pragma unroll
        for (int k = 0; k < 8; ++k) {
            float e = lrelu(a1r + av[k]) - mr;
            float x = ((byte >> k) & 1) ? __expf(e) : 0.f;
            al[k] = x * ivr;
        }
        stA = float4{al[0], al[1], al[2], al[3]};
        stB = float4{al[4], al[5], al[6], al[7]};
        u16 pk[8];
#pragma unroll
        for (int k = 0; k < 8; ++k) pk[k] = f2b(al[k]);
        *(uint4*)(Ab + buf * 8192 + row * 128 + ((cg * 16) ^ wswz)) = *(uint4*)pk;
    };

    compute_tile(0, 0);
    BARRIER_LGKM();

    for (int js = 0; js < 16; ++js) {
        const int j0 = js * 64;
        const int buf = js & 1;
        // alpha stores for tile js (values from regs), overlap with MFMA below
        float* ap = alpha + (size_t)gr * 4096 + jb + j0 + cg * 8;
        *(float4*)ap = stA;
        *(float4*)(ap + 4) = stB;
        // MFMA for tile js from buf
#pragma unroll
        for (int kh = 0; kh < 2; ++kh) {
            bf16x8 bfr[2];
#pragma unroll
            for (int nf = 0; nf < 2; ++nf) {
                int n = wv * 32 + nf * 16 + (lane & 15);
                bfr[nf] = *(const bf16x8*)(Pt + (size_t)n * 4096 + jb + j0 + kh * 32 + ((lane >> 4) << 3));
            }
#pragma unroll
            for (int mf = 0; mf < 4; ++mf) {
                int row_a = mf * 16 + (lane & 15);
                int kb = kh * 64 + ((lane >> 4) << 4);
                bf16x8 af = *(const bf16x8*)(Ab + buf * 8192 + row_a * 128 + (kb ^ ((row_a & 7) << 4)));
#pragma unroll
                for (int nf = 0; nf < 2; ++nf)
                    acc[mf][nf] = __builtin_amdgcn_mfma_f32_16x16x32_bf16(af, bfr[nf], acc[mf][nf], 0, 0, 0);
            }
        }
        // compute next tile into other buffer
        if (js < 15) compute_tile(js + 1, buf ^ 1);
        BARRIER_LGKM();
    }

    float* mp = msgpart + ((size_t)(z * 4 + blockIdx.y) * 4096 + ib) * 256;
#pragma unroll
    for (int mf = 0; mf < 4; ++mf) {
        int r0 = mf * 16 + ((lane >> 4) << 2);
#pragma unroll
        for (int nf = 0; nf < 2; ++nf) {
            int col = wv * 32 + nf * 16 + (lane & 15);
#pragma unroll
            for (int q = 0; q < 4; ++q) mp[(size_t)(r0 + q) * 256 + col] = acc[mf][nf][q];
        }
    }
}

// h_u_out = elu(soc+cnt+h_u) + aq*sigmoid(q@gW+gb)*(q@qW+qb)  -> bf16
__global__ __launch_bounds__(256) void k_post(const float* __restrict__ msgpart, const float* __restrict__ h_u,
                                              const float* __restrict__ q_u,
                                              const float* __restrict__ gate_W, const float* __restrict__ gate_b,
                                              const float* __restrict__ qproj_W, const float* __restrict__ qproj_b,
                                              const float* __restrict__ alpha_q, u16* __restrict__ huo_b) {
    int i = blockIdx.x;
    int n = threadIdx.x;
    float s = 0.f;
#pragma unroll
    for (int p = 0; p < 8; ++p) s += msgpart[((size_t)p * 4096 + i) * 256 + n];
    float v = s + h_u[(size_t)i * 256 + n];
    v = v > 0.f ? v : expm1f(v);
    float q0 = q_u[i * 4 + 0], q1 = q_u[i * 4 + 1], q2 = q_u[i * 4 + 2], q3 = q_u[i * 4 + 3];
    float g = q0 * gate_W[n] + q1 * gate_W[256 + n] + q2 * gate_W[512 + n] + q3 * gate_W[768 + n] + gate_b[n];
    g = 1.f / (1.f + __expf(-g));
    float qp = q0 * qproj_W[n] + q1 * qproj_W[256 + n] + q2 * qproj_W[512 + n] + q3 * qproj_W[768 + n] + qproj_b[n];
    float o = v + alpha_q[0] * g * qp;
    huo_b[(size_t)i * 256 + n] = f2b(o);
}

// prediction GEMM with fused gather: hid = relu(cat(huo[uidx], h_i[iidx]) @ W1 + b1)
__global__ __launch_bounds__(256) void k_pred(const u16* __restrict__ huo_b, const u16* __restrict__ h_i_b,
                                              const int* __restrict__ uidx, const int* __restrict__ iidx,
                                              const u16* __restrict__ Bt, const float* __restrict__ bias,
                                              float* __restrict__ Cf) {
    const int N = 256, K = 512;
    __shared__ u16 As[64 * 64];
    __shared__ u16 Bs[64 * 64];
    const int tid = threadIdx.x;
    const int lane = tid & 63, wv = tid >> 6;
    const int bm = blockIdx.x * 64, bn = blockIdx.y * 64;
    const int wm = (wv >> 1) * 32, wn = (wv & 1) * 32;
    f32x4 acc[2][2];
#pragma unroll
    for (int i = 0; i < 2; i++)
#pragma unroll
        for (int j = 0; j < 2; j++) acc[i][j] = f32x4{0.f, 0.f, 0.f, 0.f};

    char* Ab = (char*)As;
    char* Bb = (char*)Bs;
    const int r = tid >> 2;
    const int ib0 = (tid & 3) * 32;
    const int swz = (r & 7) << 4;
    const int uix = uidx[bm + r], iix = iidx[bm + r];

    for (int k0 = 0; k0 < K; k0 += 64) {
        int kk = k0 + (ib0 >> 1);  // element offset 0..511, 16-elem chunk
        const u16* src = (kk < 256) ? (huo_b + (size_t)uix * 256 + kk) : (h_i_b + (size_t)iix * 256 + (kk - 256));
        uint4 va0 = *(const uint4*)src;
        uint4 va1 = *(const uint4*)(src + 8);
        const uint4* gb = (const uint4*)(Bt + (size_t)(bn + r) * K + kk);
        uint4 vb0 = gb[0], vb1 = gb[1];
        __syncthreads();
        *(uint4*)(Ab + r * 128 + ((ib0) ^ swz)) = va0;
        *(uint4*)(Ab + r * 128 + ((ib0 + 16) ^ swz)) = va1;
        *(uint4*)(Bb + r * 128 + ((ib0) ^ swz)) = vb0;
        *(uint4*)(Bb + r * 128 + ((ib0 + 16) ^ swz)) = vb1;
        __syncthreads();
#pragma unroll
        for (int kh = 0; kh < 2; ++kh) {
            bf16x8 af[2], bfr[2];
#pragma unroll
            for (int mf = 0; mf < 2; ++mf) {
                int row = wm + mf * 16 + (lane & 15);
                int kb = kh * 64 + ((lane >> 4) << 4);
                af[mf] = *(const bf16x8*)(Ab + row * 128 + (kb ^ ((row & 7) << 4)));
            }
#pragma unroll
            for (int nf = 0; nf < 2; ++nf) {
                int row = wn + nf * 16 + (lane & 15);
                int kb = kh * 64 + ((lane >> 4) << 4);
                bfr[nf] = *(const bf16x8*)(Bb + row * 128 + (kb ^ ((row & 7) << 4)));
            }
#pragma unroll
            for (int mf = 0; mf < 2; ++mf)
#pragma unroll
                for (int nf = 0; nf < 2; ++nf)
                    acc[mf][nf] = __builtin_amdgcn_mfma_f32_16x16x32_bf16(af[mf], bfr[nf], acc[mf][nf], 0, 0, 0);
        }
    }
#pragma unroll
    for (int mf = 0; mf < 2; ++mf) {
#pragma unroll
        for (int nf = 0; nf < 2; ++nf) {
            int col = bn + wn + nf * 16 + (lane & 15);
            int row0 = bm + wm + mf * 16 + ((lane >> 4) << 2);
            float bv = bias[col];
#pragma unroll
            for (int q = 0; q < 4; ++q) {
                float x = fmaxf(acc[mf][nf][q] + bv, 0.f);
                Cf[(size_t)(row0 + q) * N + col] = x;
            }
        }
    }
}

__global__ __launch_bounds__(256) void k_rhat(const float* __restrict__ hid, const float* __restrict__ W2,
                                              const float* __restrict__ b2, float* __restrict__ out) {
    int row = blockIdx.x * 4 + (threadIdx.x >> 6);
    int lane = threadIdx.x & 63;
    float4 h = *(const float4*)(hid + (size_t)row * 256 + lane * 4);
    float4 w = *(const float4*)(W2 + lane * 4);
    float acc = h.x * w.x + h.y * w.y + h.z * w.z + h.w * w.w;
#pragma unroll
    for (int off = 32; off; off >>= 1) acc += __shfl_down(acc, off);
    if (lane == 0) out[row] = 1.f + 4.f / (1.f + __expf(-(acc + b2[0])));
}

extern "C" void kernel_launch(void* const* d_in, const int* in_sizes, int n_in,
                              void* d_out, int out_size, void* d_ws, size_t ws_size,
                              hipStream_t stream) {
    const float* x_u = (const float*)d_in[0];
    const float* x_i = (const float*)d_in[1];
    const int* adjS = (const int*)d_in[2];
    const int* adjC = (const int*)d_in[3];
    const int* uidx = (const int*)d_in[4];
    const int* iidx = (const int*)d_in[5];
    const float* q_u = (const float*)d_in[6];
    const float* user_W = (const float*)d_in[7];
    const float* user_b = (const float*)d_in[8];
    const float* item_W = (const float*)d_in[9];
    const float* item_b = (const float*)d_in[10];
    const float* soc_W = (const float*)d_in[11];
    const float* soc_a = (const float*)d_in[12];
    const float* cnt_W = (const float*)d_in[13];
    const float* cnt_a = (const float*)d_in[14];
    const float* gate_W = (const float*)d_in[15];
    const float* gate_b = (const float*)d_in[16];
    const float* qproj_W = (const float*)d_in[17];
    const float* qproj_b = (const float*)d_in[18];
    const float* alpha_q = (const float*)d_in[19];
    const float* pred_W1 = (const float*)d_in[20];
    const float* pred_b1 = (const float*)d_in[21];
    const float* pred_W2 = (const float*)d_in[22];
    const float* pred_b2 = (const float*)d_in[23];
    float* out = (float*)d_out;

    char* w = (char*)d_ws;
    size_t off = 0;
    auto alloc = [&](size_t bytes) -> void* {
        void* p = w + off;
        off = (off + bytes + 255) & ~(size_t)255;
        return p;
    };
    u16* x_u_b = (u16*)alloc((size_t)NU * DD * 2);
    u16* x_i_b = (u16*)alloc((size_t)NU * DD * 2);
    u16* uWt = (u16*)alloc(256 * 256 * 2);
    u16* iWt = (u16*)alloc(256 * 256 * 2);
    u16* sWt = (u16*)alloc(256 * 256 * 2);
    u16* cWt = (u16*)alloc(256 * 256 * 2);
    u16* p1Wt = (u16*)alloc(512 * 256 * 2);
    float* uvec = (float*)alloc(4 * 256 * 4);
    float* h_u_f = (float*)alloc((size_t)NU * DD * 4);
    float* h_i_f = (float*)alloc((size_t)NU * DD * 4);
    u16* h_u_b = (u16*)alloc((size_t)NU * DD * 2);
    u16* h_i_b = (u16*)alloc((size_t)NU * DD * 2);
    u16* WhT = (u16*)alloc((size_t)NU * DD * 2);
    u16* WiT = (u16*)alloc((size_t)NU * DD * 2);
    float* avec = (float*)alloc(4 * 4096 * 4);
    float* Mh = (float*)alloc(2 * 4);
    float* dpart = (float*)alloc((size_t)2 * 8 * 4096 * 4);
    float* invd = (float*)alloc((size_t)2 * 4096 * 4);
    u8* bits = (u8*)alloc((size_t)2 * 2097152);
    float* msgpart = (float*)alloc((size_t)2 * 4 * 4096 * 256 * 4);
    u16* huo_b = (u16*)alloc((size_t)NU * DD * 2);
    float* hid_f = (float*)alloc((size_t)BB * 256 * 4);
    (void)in_sizes; (void)n_in; (void)out_size; (void)ws_size;

    k_conv<<<dim3(512, 1, 2), 256, 0, stream>>>(x_u, x_u_b, x_i, x_i_b, NU * DD / 8);
    k_tconv<<<dim3(8, 4, 5), 256, 0, stream>>>(user_W, item_W, soc_W, cnt_W, pred_W1, uWt, iWt, sWt, cWt, p1Wt);
    k_uvec<<<4, 256, 0, stream>>>(soc_W, soc_a, cnt_W, cnt_a, uvec);

    k_gemm<<<dim3(64, 4, 2), 256, 0, stream>>>(x_u_b, uWt, user_b, h_u_f, h_u_b, nullptr,
                                               x_i_b, iWt, item_b, h_i_f, h_i_b, nullptr, NU, 256, 256);
    k_gemm<<<dim3(64, 4, 2), 256, 0, stream>>>(h_u_b, sWt, nullptr, nullptr, nullptr, WhT,
                                               h_i_b, cWt, nullptr, nullptr, nullptr, WiT, NU, 256, 256);

    k_gemv_a<<<64, 256, 0, stream>>>(h_u_f, h_i_f, uvec, avec);
    k_maxfinal<<<1, 256, 0, stream>>>(avec, Mh);
    k_scan<<<dim3(64, 8, 2), 256, 0, stream>>>(adjS, adjC, avec, Mh, dpart, bits);
    k_dreduce<<<32, 256, 0, stream>>>(dpart, invd);
    k_flash<<<dim3(64, 4, 2), 512, 0, stream>>>(bits, avec, Mh, invd, WhT, WiT, out, msgpart);

    k_post<<<4096, 256, 0, stream>>>(msgpart, h_u_f, q_u, gate_W, gate_b, qproj_W, qproj_b, alpha_q, huo_b);
    k_pred<<<dim3(128, 4), 256, 0, stream>>>(huo_b, h_i_b, uidx, iidx, p1Wt, pred_b1, hid_f);
    k_rhat<<<2048, 256, 0, stream>>>(hid_f, pred_W2, pred_b2, out);
}